// Round 14
// baseline (546.153 us; speedup 1.0000x reference)
//
#include <hip/hip_runtime.h>
#include <hip/hip_bf16.h>

// Problem constants (fixed by reference)
#define NN 100000      // nodes
#define NE 800000      // edges
#define EM 100         // embedding dim
#define NL 3           // layers

typedef short bf16x8 __attribute__((ext_vector_type(8)));
typedef float f32x4  __attribute__((ext_vector_type(4)));
typedef unsigned long long u64;

// role-split grid constants
#define GNE_C  3125    // deg / scatter blocks (256 threads, 1 edge/thread)
#define GW4_C  25000   // wave-per-node blocks (4 rows/block)
#define GGE_C  1563    // gemm blocks (64 rows each)
#define GCV_C  168     // weight-convert blocks (43008 elems / 256)
#define GZR_C  293     // zero-role blocks (75000 uint4 / 256)

// ---------------- workspace layout (bytes) ----------------
// m rows: 128 B = [100 x u8 biased-quant cols][f32 scale @ 100..103][pad 0x80].
// One row = 8 lanes x dwordx4 -> ONE VMEM instruction serves 8 edges.
// Softmax denominator OMITTED everywhere (global scalar, cancelled by the
// per-row L2 normalize; validated R10/R13). CNT/DGF contiguous -> zeroed by a
// k_init role (no separate memset dispatch).
static constexpr size_t OFF_XB   = 0;                               // xbf [NN*128] bf16 (K-padded rows)
static constexpr size_t OFF_M    = OFF_XB   + (size_t)NN*128*2;     // m   [NN*128] u8 rows
static constexpr size_t OFF_F    = OFF_M    + (size_t)NN*128;       // fin [NN*50] uint (bf16x2)
static constexpr size_t OFF_DEG  = OFF_F    + (size_t)NN*EM*2;      // degree [NN] f32 (decoded)
static constexpr size_t OFF_SC   = OFF_DEG  + (size_t)NN*4;         // scores [NN] f32 (holds exp(score))
static constexpr size_t OFF_ES   = OFF_SC   + (size_t)NN*4;         // es     [NE] int2 {col, raw val bits}
static constexpr size_t OFF_POS  = OFF_ES   + (size_t)NE*8;         // pos    [NE] i32 (within-row rank)
static constexpr size_t OFF_CNT  = OFF_POS  + (size_t)NE*4;         // counts [NN] i32        <- zero role
static constexpr size_t OFF_DGF  = OFF_CNT  + (size_t)NN*4;         // degfix [NN] u64        <- zero role
static constexpr size_t OFF_RP   = OFF_DGF  + (size_t)NN*8;         // rowptr [NN+1] i32
static constexpr size_t OFF_BS   = OFF_RP   + (size_t)(NN+64)*4;    // block sums [128] i32
static constexpr size_t OFF_FLAG = OFF_BS   + 512;                  // flags [4] i32 (flags[0]=emb is f32)
static constexpr size_t OFF_WAT  = OFF_FLAG + 16;                   // w_att f32 [128] (100..127 zeroed)
static constexpr size_t OFF_WBF  = OFF_WAT  + 512;                  // W bf16 [3][112][128] zero-padded

// fixed-point scale for degree accumulation
#define DEG_SCALE  4294967296.0f   // 2^32 (per-edge val < 1; sum << 2^64)
#define DEG_INV    (1.0f/4294967296.0f)

// dtype-flexible scalar load (prologue kernels only)
__device__ inline float ldf(const void* p, int i, int f32) {
    return f32 ? ((const float*)p)[i]
               : __bfloat162float(((const __hip_bfloat16*)p)[i]);
}

// unpack a packed pair of bf16 (little-endian: low ushort = element 0)
__device__ inline float bflo(unsigned int u) { return __uint_as_float(u << 16); }
__device__ inline float bfhi(unsigned int u) { return __uint_as_float(u & 0xFFFF0000u); }
// pack two floats to bf16 pair (RNE via __float2bfloat16)
__device__ inline unsigned int pack2bf(float a, float b) {
    __hip_bfloat16 ha = __float2bfloat16(a), hb = __float2bfloat16(b);
    unsigned short ua = *(unsigned short*)&ha, ub = *(unsigned short*)&hb;
    return (unsigned int)ua | ((unsigned int)ub << 16);
}
// unsigned-byte extract -> float (codegen: v_cvt_f32_ubyteN)
__device__ inline float ub0(unsigned int x) { return (float)(x & 0xFF); }
__device__ inline float ub1(unsigned int x) { return (float)((x >> 8) & 0xFF); }
__device__ inline float ub2(unsigned int x) { return (float)((x >> 16) & 0xFF); }
__device__ inline float ub3(unsigned int x) { return (float)(x >> 24); }

// ---------------- inline dtype probe (per block, wave 0, LDS broadcast) ----------
__device__ inline int probe_block(const void* p, int nsamp) {
    __shared__ int sflag;
    int tid = threadIdx.x;
    if (tid < 64) {
        const unsigned short* h = (const unsigned short*)p;
        int big = 0;
        for (int i = tid; i < nsamp; i += 64) {
            int ex = (h[2 * i] >> 7) & 0xFF;
            big += (ex >= 134) ? 1 : 0;
        }
        #pragma unroll
        for (int off = 32; off; off >>= 1) big += __shfl_xor(big, off);
        if (tid == 0) sflag = (big >= 2) ? 1 : 0;
    }
    __syncthreads();
    int f = sflag;
    __syncthreads();
    return f;
}

// ---------------- fused init: initxf || weight-convert || zero counts/degfix ----
//   [0, GW4_C)                    : xbf/fin init, scores[r] = exp(dot(emb,w_att))
//   [GW4_C, +GCV_C)               : wat (f32, padded) + W -> bf16 [3][112][128]
//   [GW4_C+GCV_C, +GZR_C)         : zero counts+degfix (1.2 MB, uint4 stores)
// deg is deliberately NOT fused here: R7 measured that streaming co-tenants slow
// the memory-side atomic phase by ~35us.
__global__ __launch_bounds__(256) void k_init(const void* __restrict__ emb,
                                              const void* __restrict__ w_att,
                                              const void* __restrict__ w_itm,
                                              unsigned int* __restrict__ xbf,
                                              unsigned int* __restrict__ fin,
                                              float* __restrict__ scores, int* flags,
                                              float* __restrict__ wat,
                                              unsigned short* __restrict__ wbf,
                                              unsigned int* __restrict__ zbase) {
    int b = blockIdx.x;
    if (b < GW4_C) {
        // ---- initxf role ----
        int femb = probe_block(emb, 256);
        int fw = probe_block(w_att, 50);
        if (b == 0 && threadIdx.x == 0) flags[0] = femb;
        int lane = threadIdx.x & 63, w = threadIdx.x >> 6;
        int r = b * 4 + w;                    // exact: r < NN always
        float f0 = 0.f, f1 = 0.f, part = 0.f;
        bool act = lane < 50;
        if (act) {
            if (femb) {
                float2 t = ((const float2*)emb)[(size_t)r * 50 + lane];
                f0 = t.x; f1 = t.y;
            } else {
                unsigned int u = ((const unsigned int*)emb)[(size_t)r * 50 + lane];
                f0 = bflo(u); f1 = bfhi(u);
            }
            float w0 = ldf(w_att, 2 * lane, fw);
            float w1 = ldf(w_att, 2 * lane + 1, fw);
            part = f0 * w0 + f1 * w1;
            fin[(size_t)r * 50 + lane] = pack2bf(f0, f1);
        }
        xbf[(size_t)r * 64 + lane] = act ? pack2bf(f0, f1) : 0u;  // lanes 50..63 = K pad
        #pragma unroll
        for (int off = 32; off; off >>= 1) part += __shfl_xor(part, off);
        if (lane == 0) scores[r] = expf(part);
    } else if (b < GW4_C + GCV_C) {
        // ---- weight-convert role ----
        int fw = probe_block(w_att, 50);
        int fi = probe_block(w_itm, 256);
        int i = (b - GW4_C) * 256 + threadIdx.x;
        if (i < 128) wat[i] = (i < EM) ? ldf(w_att, i, fw) : 0.f;   // pad 100..127 = 0
        if (i < NL * 112 * 128) {
            int l = i / (112 * 128), rem = i % (112 * 128);
            int n = rem >> 7, k = rem & 127;
            float v = (n < EM && k < EM) ? ldf(w_itm, (l * EM + n) * EM + k, fi) : 0.f;
            __hip_bfloat16 bb = __float2bfloat16(v);
            wbf[i] = *(unsigned short*)&bb;
        }
    } else {
        // ---- zero role: counts (400KB) + degfix (800KB), contiguous ----
        int i = (b - GW4_C - GCV_C) * 256 + threadIdx.x;
        if (i < 75000) ((uint4*)zbase)[i] = make_uint4(0u, 0u, 0u, 0u);
    }
}

// ---------------- degree + row histogram/rank (atomics ONLY, nothing co-runs) ---
// R9 form: the rank-returning counts atomic lives here (solo kernel) so the
// scatter in k_sg is atomic-free and hides fully under gemm0.
__global__ __launch_bounds__(256) void k_deg(const void* __restrict__ val,
                                             const int* __restrict__ row, const int* __restrict__ col,
                                             u64* degfix, int* counts, int* __restrict__ pos) {
    int fav = probe_block(val, 256);
    int e = blockIdx.x * 256 + threadIdx.x;
    if (e >= NE) return;
    float v = ldf(val, e, fav);
    atomicAdd(&degfix[col[e]], (u64)llrintf(v * DEG_SCALE));
    pos[e] = atomicAdd(&counts[row[e]], 1);
}

// ---------------- exclusive scan of counts -> rowptr; decode degfix -> deg ------
__global__ __launch_bounds__(256) void k_scanA(const int* __restrict__ counts, int* excl, int* bsum,
                                               const u64* __restrict__ degfix, float* __restrict__ deg) {
    __shared__ int s[256];
    int base = blockIdx.x * 1024;
    int tid = threadIdx.x;
    int v[4]; int t = 0;
    #pragma unroll
    for (int i = 0; i < 4; i++) {
        int idx = base + tid * 4 + i;
        v[i] = (idx < NN) ? counts[idx] : 0;
        if (idx < NN) deg[idx] = (float)degfix[idx] * DEG_INV;
        t += v[i];
    }
    s[tid] = t; __syncthreads();
    for (int off = 1; off < 256; off <<= 1) {
        int add = (tid >= off) ? s[tid - off] : 0;
        __syncthreads();
        s[tid] += add;
        __syncthreads();
    }
    int ex = (tid == 0) ? 0 : s[tid - 1];
    #pragma unroll
    for (int i = 0; i < 4; i++) {
        int idx = base + tid * 4 + i;
        if (idx < NN) excl[idx] = ex;
        ex += v[i];
    }
    if (tid == 255) bsum[blockIdx.x] = s[255];
}

__global__ __launch_bounds__(256) void k_scanC(int* rowptr, const int* __restrict__ bsum) {
    __shared__ int spfx;
    int tid = threadIdx.x;
    int gi = blockIdx.x >> 2;   // this block's 1024-group index
    if (tid < 64) {
        int t = (tid < gi) ? bsum[tid] : 0;
        if (tid + 64 < gi) t += bsum[tid + 64];
        #pragma unroll
        for (int off = 32; off; off >>= 1) t += __shfl_xor(t, off);
        if (tid == 0) spfx = t;
    }
    __syncthreads();
    int pfx = spfx;
    int i = blockIdx.x * 256 + tid;
    if (i < NN) {
        rowptr[i] += pfx;
        if (i == 0) rowptr[NN] = NE;
    }
}

// ---------------- gemm body: m = biased-u8 quant of (x @ W^T), per-row scale ----
// One wave per 16 rows; K=100 padded to 128 (4x mfma_f32_16x16x32_bf16);
// N=100 as 7x16 tiles. Row r quantized with mx = rowmax|acc| (16-lane shfl
// reduce): byte = rint(acc*127/mx)+128; scale = att_r*mx/127 stored at bytes
// 100..103; pad bytes 104..127 = 0x80 (biased zero). att folds exp(score) and
// 1/deg[node] -- NO softmax denominator (cancelled by L2 norm, see header).
__device__ void gemm_body(int gb, const unsigned short* __restrict__ xbf,
                          const unsigned short* __restrict__ wbf,
                          const float* __restrict__ scores,
                          const float* __restrict__ deg,
                          unsigned char* __restrict__ m, int layer) {
    int wid = threadIdx.x >> 6, lane = threadIdx.x & 63;
    int row0 = gb * 64 + wid * 16;
    if (row0 >= NN) return;                 // NN = 16*6250: no partial row tiles
    int c15 = lane & 15, quad = lane >> 4;

    const bf16x8* xa = (const bf16x8*)(xbf + (size_t)(row0 + c15) * 128 + quad * 8);
    bf16x8 a[4];
    #pragma unroll
    for (int kq = 0; kq < 4; kq++) a[kq] = xa[kq * 4];   // +32 bf16 per kq

    float att[4];
    #pragma unroll
    for (int r = 0; r < 4; r++) {
        int grow = row0 + quad * 4 + r;
        float dv = deg[grow];
        float invd = dv > 0.f ? 1.0f / dv : 0.f;
        att[r] = scores[grow] * invd;
    }

    const bf16x8* wb = (const bf16x8*)(wbf + (size_t)layer * 112 * 128
                                       + (size_t)c15 * 128 + quad * 8);
    f32x4 accs[7];
    #pragma unroll
    for (int nt = 0; nt < 7; nt++) {
        f32x4 acc = {0.f, 0.f, 0.f, 0.f};
        #pragma unroll
        for (int kq = 0; kq < 4; kq++) {
            bf16x8 b = wb[nt * 256 + kq * 4];   // +16 rows*128 per nt, +32 bf16 per kq
            acc = __builtin_amdgcn_mfma_f32_16x16x32_bf16(a[kq], b, acc, 0, 0, 0);
        }
        accs[nt] = acc;
    }
    #pragma unroll
    for (int r = 0; r < 4; r++) {
        float mx = 0.f;
        #pragma unroll
        for (int nt = 0; nt < 7; nt++) mx = fmaxf(mx, fabsf(accs[nt][r]));
        #pragma unroll
        for (int off = 1; off < 16; off <<= 1) mx = fmaxf(mx, __shfl_xor(mx, off));
        float inv = 127.0f / fmaxf(mx, 1e-30f);
        int grow = row0 + quad * 4 + r;
        unsigned char* rowp = m + (size_t)grow * 128;
        #pragma unroll
        for (int nt = 0; nt < 7; nt++) {
            int col = nt * 16 + c15;
            if (col < EM) {
                int q = (int)rintf(accs[nt][r] * inv) + 128;
                rowp[col] = (unsigned char)q;
            }
        }
        if (c15 == 0) *(float*)(rowp + 100) = att[r] * mx * (1.0f / 127.0f);
        if (c15 < 6)  *(unsigned int*)(rowp + 104 + 4 * c15) = 0x80808080u;  // biased-zero pad
    }
}

__global__ __launch_bounds__(256) void k_gemm(const unsigned short* __restrict__ xbf,
                                              const unsigned short* __restrict__ wbf,
                                              const float* __restrict__ scores,
                                              const float* __restrict__ deg,
                                              unsigned char* __restrict__ m, int layer) {
    gemm_body(blockIdx.x, xbf, wbf, scores, deg, m, layer);
}

// ---------------- fused: CSR scatter (atomic-FREE, rowptr+pos) || gemm layer 0 --
//   [0, GNE_C)        : es[rowptr[row]+pos] = {col, raw val}
//   [GNE_C, +GGE_C)   : gemm layer 0
__global__ __launch_bounds__(256) void k_sg(const int* __restrict__ row, const int* __restrict__ col,
                                            const void* __restrict__ aval,
                                            const int* __restrict__ rowptr,
                                            const int* __restrict__ pos, int2* __restrict__ es,
                                            const unsigned short* __restrict__ xbf,
                                            const unsigned short* __restrict__ wbf,
                                            const float* __restrict__ scores,
                                            const float* __restrict__ deg,
                                            unsigned char* __restrict__ m) {
    int b = blockIdx.x;
    if (b < GNE_C) {
        int fav = probe_block(aval, 256);
        int e = b * 256 + threadIdx.x;
        if (e >= NE) return;
        int p = rowptr[row[e]] + pos[e];
        es[p] = make_int2(col[e], __float_as_int(ldf(aval, e, fav)));
    } else {
        gemm_body(b - GNE_C, xbf, wbf, scores, deg, m, 0);
    }
}

// ---------------- per-layer: SpMM gather, 8 edges per VMEM instruction ----------
// Lane (slot=lane>>3, k8=lane&7). 8 lanes x dwordx4 = full 128 B row -> ONE
// gather instruction covers 8 edges (vs 2 before). Per 16-edge iter: 2 es
// dwordx2 + 2 dwordx4 gathers in flight; P(deg<=16)=99.7% -> one straight-line
// iteration for nearly all rows (4 VMEM/row total). Lane k8 holds cols
// 16k8..16k8+15; scale rides in lane k8==6's word .y (bytes 100..103),
// broadcast via __shfl, masked to biased-zero for dequant. Biased dequant:
// acc = sum t*q, corrected by -128*sum(t). Dummy slots clamp to edge e-1 with
// weight 0. Fused: L2-normalize, fin RMW, next-layer exp(score), last output.
__global__ __launch_bounds__(256) void k_spmm(const int* __restrict__ rowptr,
                                              const int2* __restrict__ es,
                                              const unsigned char* __restrict__ m,
                                              const float* __restrict__ wat,
                                              unsigned int* __restrict__ xbf,
                                              unsigned int* __restrict__ fin,
                                              float* __restrict__ scores,
                                              void* __restrict__ out, const int* flags,
                                              int last) {
    int lane = threadIdx.x & 63;
    int w = threadIdx.x >> 6;
    int r = blockIdx.x * 4 + w;               // grid exact: r < NN always
    int slot = lane >> 3, k8 = lane & 7;
    int s = rowptr[r], e = rowptr[r + 1];
    const char* mq = (const char*)m;
    int src6 = (lane & 56) + 6;               // scale-holder lane of this 8-group

    float acc[16];
    #pragma unroll
    for (int t = 0; t < 16; t++) acc[t] = 0.f;
    float tsum = 0.f;
    for (int i = s; i < e; i += 16) {
        int i0 = i + slot, i1 = i + 8 + slot;
        int j0 = i0 < e - 1 ? i0 : e - 1;
        int j1 = i1 < e - 1 ? i1 : e - 1;
        int2 c0 = es[j0];
        int2 c1 = es[j1];
        float v0 = (i0 < e) ? __int_as_float(c0.y) : 0.f;
        float v1 = (i1 < e) ? __int_as_float(c1.y) : 0.f;
        uint4 u0 = *(const uint4*)(mq + (((size_t)c0.x) << 7) + (k8 << 4));
        uint4 u1 = *(const uint4*)(mq + (((size_t)c1.x) << 7) + (k8 << 4));
        float s0 = __uint_as_float(__shfl((int)u0.y, src6));
        float s1 = __uint_as_float(__shfl((int)u1.y, src6));
        float t0 = v0 * s0, t1 = v1 * s1;
        tsum += t0 + t1;
        if (k8 == 6) { u0.y = 0x80808080u; u1.y = 0x80808080u; }  // mask scale word
        const unsigned int* p0 = (const unsigned int*)&u0;
        const unsigned int* p1 = (const unsigned int*)&u1;
        #pragma unroll
        for (int q = 0; q < 4; q++) {
            acc[4*q+0] += t0 * ub0(p0[q]); acc[4*q+1] += t0 * ub1(p0[q]);
            acc[4*q+2] += t0 * ub2(p0[q]); acc[4*q+3] += t0 * ub3(p0[q]);
        }
        #pragma unroll
        for (int q = 0; q < 4; q++) {
            acc[4*q+0] += t1 * ub0(p1[q]); acc[4*q+1] += t1 * ub1(p1[q]);
            acc[4*q+2] += t1 * ub2(p1[q]); acc[4*q+3] += t1 * ub3(p1[q]);
        }
    }
    // reduce across the 8 edge slots (lane bits 3..5); then remove the +128 bias
    #pragma unroll
    for (int t = 0; t < 16; t++) {
        acc[t] += __shfl_xor(acc[t], 8);
        acc[t] += __shfl_xor(acc[t], 16);
        acc[t] += __shfl_xor(acc[t], 32);
    }
    tsum += __shfl_xor(tsum, 8);
    tsum += __shfl_xor(tsum, 16);
    tsum += __shfl_xor(tsum, 32);
    float corr = 128.0f * tsum;
    #pragma unroll
    for (int t = 0; t < 16; t++) acc[t] -= corr;

    // L2 norm over the row (pad cols ~0; they feed zeroed W rows only)
    float sq = 0.f;
    #pragma unroll
    for (int t = 0; t < 16; t++) sq += acc[t] * acc[t];
    sq += __shfl_xor(sq, 4);
    sq += __shfl_xor(sq, 2);
    sq += __shfl_xor(sq, 1);
    float rn = 1.f / fmaxf(sqrtf(sq), 1e-12f);
    float n[16];
    #pragma unroll
    for (int t = 0; t < 16; t++) n[t] = acc[t] * rn;

    float part = 0.f;
    if (slot == 0) {                          // lanes 0..7; lane == k8
        if (!last) {
            uint4 qa, qb;
            qa.x = pack2bf(n[0], n[1]);   qa.y = pack2bf(n[2], n[3]);
            qa.z = pack2bf(n[4], n[5]);   qa.w = pack2bf(n[6], n[7]);
            qb.x = pack2bf(n[8], n[9]);   qb.y = pack2bf(n[10], n[11]);
            qb.z = pack2bf(n[12], n[13]); qb.w = pack2bf(n[14], n[15]);
            uint4* xb = (uint4*)(xbf + (size_t)r * 64 + lane * 8);
            xb[0] = qa; xb[1] = qb;
            // next-layer score partial (wat zero-padded: pad cols contribute 0)
            #pragma unroll
            for (int t = 0; t < 16; t += 4) {
                float4 wv = *(const float4*)(wat + lane * 16 + t);
                part += n[t] * wv.x + n[t+1] * wv.y + n[t+2] * wv.z + n[t+3] * wv.w;
            }
        }
        // fin RMW: uints 8*lane..8*lane+7; valid: lane<6 all 8, lane==6 first 2
        if (lane < 7) {
            size_t fb = (size_t)r * 50 + lane * 8;
            int nu = (lane < 6) ? 8 : 2;
            unsigned int fu[8] = {0u,0u,0u,0u,0u,0u,0u,0u};
            #pragma unroll
            for (int t = 0; t < 8; t += 2) {
                if (t < nu) { uint2 p = *(const uint2*)(fin + fb + t); fu[t] = p.x; fu[t+1] = p.y; }
            }
            float fn[16];
            #pragma unroll
            for (int t = 0; t < 8; t++) {
                fn[2*t]   = bflo(fu[t]) + n[2*t];
                fn[2*t+1] = bfhi(fu[t]) + n[2*t+1];
            }
            if (!last) {
                #pragma unroll
                for (int t = 0; t < 8; t += 2) {
                    if (t < nu) {
                        uint2 p;
                        p.x = pack2bf(fn[2*t],   fn[2*t+1]);
                        p.y = pack2bf(fn[2*t+2], fn[2*t+3]);
                        *(uint2*)(fin + fb + t) = p;
                    }
                }
            } else {
                if (flags[0]) {
                    float* ob = (float*)out + (size_t)r * 100 + lane * 16;
                    #pragma unroll
                    for (int t = 0; t < 16; t += 4) {
                        if (t < 2 * nu) {
                            float4 A;
                            A.x = fn[t]   * 0.25f; A.y = fn[t+1] * 0.25f;
                            A.z = fn[t+2] * 0.25f; A.w = fn[t+3] * 0.25f;
                            *(float4*)(ob + t) = A;
                        }
                    }
                } else {
                    unsigned int* ob = (unsigned int*)out + (size_t)r * 50 + lane * 8;
                    #pragma unroll
                    for (int t = 0; t < 8; t += 2) {
                        if (t < nu) {
                            uint2 p;
                            p.x = pack2bf(fn[2*t]   * 0.25f, fn[2*t+1] * 0.25f);
                            p.y = pack2bf(fn[2*t+2] * 0.25f, fn[2*t+3] * 0.25f);
                            *(uint2*)(ob + t) = p;
                        }
                    }
                }
            }
        }
    }
    if (!last) {
        part += __shfl_xor(part, 4);
        part += __shfl_xor(part, 2);
        part += __shfl_xor(part, 1);
        if (lane == 0) scores[r] = expf(part);
    }
}

extern "C" void kernel_launch(void* const* d_in, const int* in_sizes, int n_in,
                              void* d_out, int out_size, void* d_ws, size_t ws_size,
                              hipStream_t stream) {
    const void* emb   = d_in[0];
    const void* aval  = d_in[1];
    const void* w_att = d_in[2];
    const void* w_itm = d_in[4];
    const int* arow = (const int*)d_in[5];
    const int* acol = (const int*)d_in[6];

    char* w = (char*)d_ws;
    unsigned int*   xbf    = (unsigned int*)(w + OFF_XB);
    unsigned char*  m      = (unsigned char*)(w + OFF_M);
    unsigned int*   fin    = (unsigned int*)(w + OFF_F);
    float*          deg    = (float*)(w + OFF_DEG);
    float*          scores = (float*)(w + OFF_SC);
    int2*           es     = (int2*) (w + OFF_ES);
    int*            pos    = (int*)  (w + OFF_POS);
    int*            counts = (int*)  (w + OFF_CNT);
    u64*            degfix = (u64*)  (w + OFF_DGF);
    int*            rowptr = (int*)  (w + OFF_RP);
    int*            bsum   = (int*)  (w + OFF_BS);
    int*            flags  = (int*)  (w + OFF_FLAG);
    float*          wat    = (float*)(w + OFF_WAT);
    unsigned short* wbf    = (unsigned short*)(w + OFF_WBF);

    const int GN   = (NN + 255) / 256;        // 391 (scanC)
    const int GSCN = (NN + 1023) / 1024;      // 98 scan blocks
    const int GINI = GW4_C + GCV_C + GZR_C;   // init blocks incl. zero role
    const int GSG  = GNE_C + GGE_C;           // 4688 scatter||gemm0 blocks

    k_init<<<GINI, 256, 0, stream>>>(emb, w_att, w_itm, xbf, fin, scores, flags,
                                     wat, wbf, (unsigned int*)(w + OFF_CNT));
    k_deg<<<GNE_C, 256, 0, stream>>>(aval, arow, acol, degfix, counts, pos);
    k_scanA<<<GSCN, 256, 0, stream>>>(counts, rowptr, bsum, degfix, deg);
    k_scanC<<<GN, 256, 0, stream>>>(rowptr, bsum);
    k_sg<<<GSG, 256, 0, stream>>>(arow, acol, aval, rowptr, pos, es,
                                  (const unsigned short*)xbf, wbf, scores, deg, m);

    k_spmm<<<GW4_C, 256, 0, stream>>>(rowptr, es, m, wat, xbf, fin, scores,
                                      d_out, flags, 0);
    for (int l = 1; l < NL; l++) {
        k_gemm<<<GGE_C, 256, 0, stream>>>((const unsigned short*)xbf, wbf, scores, deg, m, l);
        k_spmm<<<GW4_C, 256, 0, stream>>>(rowptr, es, m, wat, xbf, fin, scores,
                                          d_out, flags, (l == NL - 1) ? 1 : 0);
    }
}

// Round 15
// 474.290 us; speedup vs baseline: 1.1515x; 1.1515x over previous
//
#include <hip/hip_runtime.h>
#include <hip/hip_bf16.h>

// Problem constants (fixed by reference)
#define NN 100000      // nodes
#define NE 800000      // edges
#define EM 100         // embedding dim
#define NL 3           // layers

typedef short bf16x8 __attribute__((ext_vector_type(8)));
typedef float f32x4  __attribute__((ext_vector_type(4)));
typedef unsigned long long u64;

// role-split grid constants
#define GNE_C  3125    // deg / scatter blocks (256 threads, 1 edge/thread)
#define GW4_C  25000   // wave-per-node blocks (4 rows/block)
#define GGE_C  1563    // gemm blocks (64 rows each)
#define GCV_C  168     // weight-convert blocks (43008 elems / 256)

// ---------------- workspace layout (bytes) ----------------
// m rows: 128 B = [100 x u8 biased-quant cols][f32 scale @ 100..103][pad 0x80].
// One row = 16 lanes x dwordx2 -> one VMEM instruction, 2 cache lines.
// (R14 measured: 8-lane x dwordx4 regresses -- spmm goes VALU-bound at 77%.)
// Softmax denominator OMITTED everywhere: it is a global positive scalar
// multiplying each pre-norm row and the per-row L2 normalize cancels it exactly
// (it rides in the f32 row scale). Validated R10/R13.
// CNT/DGF contiguous -> a single hipMemsetAsync zeroes both.
static constexpr size_t OFF_XB   = 0;                               // xbf [NN*128] bf16 (K-padded rows)
static constexpr size_t OFF_M    = OFF_XB   + (size_t)NN*128*2;     // m   [NN*128] u8 rows
static constexpr size_t OFF_F    = OFF_M    + (size_t)NN*128;       // fin [NN*50] uint (bf16x2)
static constexpr size_t OFF_DEG  = OFF_F    + (size_t)NN*EM*2;      // degree [NN] f32 (decoded)
static constexpr size_t OFF_SC   = OFF_DEG  + (size_t)NN*4;         // scores [NN] f32 (holds exp(score))
static constexpr size_t OFF_ES   = OFF_SC   + (size_t)NN*4;         // es     [NE] int2 {col, raw val bits}
static constexpr size_t OFF_POS  = OFF_ES   + (size_t)NE*8;         // pos    [NE] i32 (within-row rank)
static constexpr size_t OFF_CNT  = OFF_POS  + (size_t)NE*4;         // counts [NN] i32        <- memset 0
static constexpr size_t OFF_DGF  = OFF_CNT  + (size_t)NN*4;         // degfix [NN] u64        <- memset 0
static constexpr size_t OFF_RP   = OFF_DGF  + (size_t)NN*8;         // rowptr [NN+1] i32
static constexpr size_t OFF_BS   = OFF_RP   + (size_t)(NN+64)*4;    // block sums [128] i32
static constexpr size_t OFF_FLAG = OFF_BS   + 512;                  // flags [4] i32 (flags[0]=emb is f32)
static constexpr size_t OFF_WAT  = OFF_FLAG + 16;                   // w_att f32 [128] (100..127 zeroed)
static constexpr size_t OFF_WBF  = OFF_WAT  + 512;                  // W bf16 [3][112][128] zero-padded
static constexpr size_t ZERO_BYTES = (size_t)NN*4 + (size_t)NN*8;   // counts + degfix

// fixed-point scale for degree accumulation
#define DEG_SCALE  4294967296.0f   // 2^32 (per-edge val < 1; sum << 2^64)
#define DEG_INV    (1.0f/4294967296.0f)

// dtype-flexible scalar load (prologue kernels only)
__device__ inline float ldf(const void* p, int i, int f32) {
    return f32 ? ((const float*)p)[i]
               : __bfloat162float(((const __hip_bfloat16*)p)[i]);
}

// unpack a packed pair of bf16 (little-endian: low ushort = element 0)
__device__ inline float bflo(unsigned int u) { return __uint_as_float(u << 16); }
__device__ inline float bfhi(unsigned int u) { return __uint_as_float(u & 0xFFFF0000u); }
// pack two floats to bf16 pair (RNE via __float2bfloat16)
__device__ inline unsigned int pack2bf(float a, float b) {
    __hip_bfloat16 ha = __float2bfloat16(a), hb = __float2bfloat16(b);
    unsigned short ua = *(unsigned short*)&ha, ub = *(unsigned short*)&hb;
    return (unsigned int)ua | ((unsigned int)ub << 16);
}
// unsigned-byte extract -> float (codegen: v_cvt_f32_ubyteN)
__device__ inline float ub0(unsigned int x) { return (float)(x & 0xFF); }
__device__ inline float ub1(unsigned int x) { return (float)((x >> 8) & 0xFF); }
__device__ inline float ub2(unsigned int x) { return (float)((x >> 16) & 0xFF); }
__device__ inline float ub3(unsigned int x) { return (float)(x >> 24); }

// ---------------- inline dtype probe (per block, wave 0, LDS broadcast) ----------
__device__ inline int probe_block(const void* p, int nsamp) {
    __shared__ int sflag;
    int tid = threadIdx.x;
    if (tid < 64) {
        const unsigned short* h = (const unsigned short*)p;
        int big = 0;
        for (int i = tid; i < nsamp; i += 64) {
            int ex = (h[2 * i] >> 7) & 0xFF;
            big += (ex >= 134) ? 1 : 0;
        }
        #pragma unroll
        for (int off = 32; off; off >>= 1) big += __shfl_xor(big, off);
        if (tid == 0) sflag = (big >= 2) ? 1 : 0;
    }
    __syncthreads();
    int f = sflag;
    __syncthreads();
    return f;
}

// ---------------- fused init: initxf || weight-convert (NO atomic-heavy role) ---
//   [0, GW4_C)            : xbf/fin init, scores[r] = exp(dot(emb, w_att))
//   [GW4_C, GW4_C+GCV_C)  : wat (f32, padded) + W -> bf16 [3][112][128]
// deg is deliberately NOT fused here: R7 measured that streaming co-tenants slow
// the memory-side atomic phase by ~35us.
__global__ __launch_bounds__(256) void k_init(const void* __restrict__ emb,
                                              const void* __restrict__ w_att,
                                              const void* __restrict__ w_itm,
                                              unsigned int* __restrict__ xbf,
                                              unsigned int* __restrict__ fin,
                                              float* __restrict__ scores, int* flags,
                                              float* __restrict__ wat,
                                              unsigned short* __restrict__ wbf) {
    int b = blockIdx.x;
    if (b < GW4_C) {
        // ---- initxf role ----
        int femb = probe_block(emb, 256);
        int fw = probe_block(w_att, 50);
        if (b == 0 && threadIdx.x == 0) flags[0] = femb;
        int lane = threadIdx.x & 63, w = threadIdx.x >> 6;
        int r = b * 4 + w;                    // exact: r < NN always
        float f0 = 0.f, f1 = 0.f, part = 0.f;
        bool act = lane < 50;
        if (act) {
            if (femb) {
                float2 t = ((const float2*)emb)[(size_t)r * 50 + lane];
                f0 = t.x; f1 = t.y;
            } else {
                unsigned int u = ((const unsigned int*)emb)[(size_t)r * 50 + lane];
                f0 = bflo(u); f1 = bfhi(u);
            }
            float w0 = ldf(w_att, 2 * lane, fw);
            float w1 = ldf(w_att, 2 * lane + 1, fw);
            part = f0 * w0 + f1 * w1;
            fin[(size_t)r * 50 + lane] = pack2bf(f0, f1);
        }
        xbf[(size_t)r * 64 + lane] = act ? pack2bf(f0, f1) : 0u;  // lanes 50..63 = K pad
        #pragma unroll
        for (int off = 32; off; off >>= 1) part += __shfl_xor(part, off);
        if (lane == 0) scores[r] = expf(part);
    } else {
        // ---- weight-convert role ----
        int fw = probe_block(w_att, 50);
        int fi = probe_block(w_itm, 256);
        int i = (b - GW4_C) * 256 + threadIdx.x;
        if (i < 128) wat[i] = (i < EM) ? ldf(w_att, i, fw) : 0.f;   // pad 100..127 = 0
        if (i < NL * 112 * 128) {
            int l = i / (112 * 128), rem = i % (112 * 128);
            int n = rem >> 7, k = rem & 127;
            float v = (n < EM && k < EM) ? ldf(w_itm, (l * EM + n) * EM + k, fi) : 0.f;
            __hip_bfloat16 bb = __float2bfloat16(v);
            wbf[i] = *(unsigned short*)&bb;
        }
    }
}

// ---------------- degree + row histogram/rank (atomics ONLY, nothing co-runs) ---
// R9 form: the rank-returning counts atomic lives here (solo kernel) so the
// scatter in k_sg is atomic-free and hides fully under gemm0. Measured best
// total topology (491us R9, 476us R13) vs rank-in-scatter (503us, R10).
__global__ __launch_bounds__(256) void k_deg(const void* __restrict__ val,
                                             const int* __restrict__ row, const int* __restrict__ col,
                                             u64* degfix, int* counts, int* __restrict__ pos) {
    int fav = probe_block(val, 256);
    int e = blockIdx.x * 256 + threadIdx.x;
    if (e >= NE) return;
    float v = ldf(val, e, fav);
    atomicAdd(&degfix[col[e]], (u64)llrintf(v * DEG_SCALE));
    pos[e] = atomicAdd(&counts[row[e]], 1);
}

// ---------------- exclusive scan of counts -> rowptr; decode degfix -> deg ------
__global__ __launch_bounds__(256) void k_scanA(const int* __restrict__ counts, int* excl, int* bsum,
                                               const u64* __restrict__ degfix, float* __restrict__ deg) {
    __shared__ int s[256];
    int base = blockIdx.x * 1024;
    int tid = threadIdx.x;
    int v[4]; int t = 0;
    #pragma unroll
    for (int i = 0; i < 4; i++) {
        int idx = base + tid * 4 + i;
        v[i] = (idx < NN) ? counts[idx] : 0;
        if (idx < NN) deg[idx] = (float)degfix[idx] * DEG_INV;
        t += v[i];
    }
    s[tid] = t; __syncthreads();
    for (int off = 1; off < 256; off <<= 1) {
        int add = (tid >= off) ? s[tid - off] : 0;
        __syncthreads();
        s[tid] += add;
        __syncthreads();
    }
    int ex = (tid == 0) ? 0 : s[tid - 1];
    #pragma unroll
    for (int i = 0; i < 4; i++) {
        int idx = base + tid * 4 + i;
        if (idx < NN) excl[idx] = ex;
        ex += v[i];
    }
    if (tid == 255) bsum[blockIdx.x] = s[255];
}

__global__ __launch_bounds__(256) void k_scanC(int* rowptr, const int* __restrict__ bsum) {
    __shared__ int spfx;
    int tid = threadIdx.x;
    int gi = blockIdx.x >> 2;   // this block's 1024-group index
    if (tid < 64) {
        int t = (tid < gi) ? bsum[tid] : 0;
        if (tid + 64 < gi) t += bsum[tid + 64];
        #pragma unroll
        for (int off = 32; off; off >>= 1) t += __shfl_xor(t, off);
        if (tid == 0) spfx = t;
    }
    __syncthreads();
    int pfx = spfx;
    int i = blockIdx.x * 256 + tid;
    if (i < NN) {
        rowptr[i] += pfx;
        if (i == 0) rowptr[NN] = NE;
    }
}

// ---------------- gemm body: m = biased-u8 quant of (x @ W^T), per-row scale ----
// One wave per 16 rows; K=100 padded to 128 (4x mfma_f32_16x16x32_bf16);
// N=100 as 7x16 tiles. Row r quantized with mx = rowmax|acc| (16-lane shfl
// reduce): byte = rint(acc*127/mx)+128; scale = att_r*mx/127 stored at bytes
// 100..103; pad bytes 104..127 = 0x80 (biased zero). att folds exp(score) and
// 1/deg[node] -- NO softmax denominator (cancelled by L2 norm, see header).
__device__ void gemm_body(int gb, const unsigned short* __restrict__ xbf,
                          const unsigned short* __restrict__ wbf,
                          const float* __restrict__ scores,
                          const float* __restrict__ deg,
                          unsigned char* __restrict__ m, int layer) {
    int wid = threadIdx.x >> 6, lane = threadIdx.x & 63;
    int row0 = gb * 64 + wid * 16;
    if (row0 >= NN) return;                 // NN = 16*6250: no partial row tiles
    int c15 = lane & 15, quad = lane >> 4;

    const bf16x8* xa = (const bf16x8*)(xbf + (size_t)(row0 + c15) * 128 + quad * 8);
    bf16x8 a[4];
    #pragma unroll
    for (int kq = 0; kq < 4; kq++) a[kq] = xa[kq * 4];   // +32 bf16 per kq

    float att[4];
    #pragma unroll
    for (int r = 0; r < 4; r++) {
        int grow = row0 + quad * 4 + r;
        float dv = deg[grow];
        float invd = dv > 0.f ? 1.0f / dv : 0.f;
        att[r] = scores[grow] * invd;
    }

    const bf16x8* wb = (const bf16x8*)(wbf + (size_t)layer * 112 * 128
                                       + (size_t)c15 * 128 + quad * 8);
    f32x4 accs[7];
    #pragma unroll
    for (int nt = 0; nt < 7; nt++) {
        f32x4 acc = {0.f, 0.f, 0.f, 0.f};
        #pragma unroll
        for (int kq = 0; kq < 4; kq++) {
            bf16x8 b = wb[nt * 256 + kq * 4];   // +16 rows*128 per nt, +32 bf16 per kq
            acc = __builtin_amdgcn_mfma_f32_16x16x32_bf16(a[kq], b, acc, 0, 0, 0);
        }
        accs[nt] = acc;
    }
    #pragma unroll
    for (int r = 0; r < 4; r++) {
        float mx = 0.f;
        #pragma unroll
        for (int nt = 0; nt < 7; nt++) mx = fmaxf(mx, fabsf(accs[nt][r]));
        #pragma unroll
        for (int off = 1; off < 16; off <<= 1) mx = fmaxf(mx, __shfl_xor(mx, off));
        float inv = 127.0f / fmaxf(mx, 1e-30f);
        int grow = row0 + quad * 4 + r;
        unsigned char* rowp = m + (size_t)grow * 128;
        #pragma unroll
        for (int nt = 0; nt < 7; nt++) {
            int col = nt * 16 + c15;
            if (col < EM) {
                int q = (int)rintf(accs[nt][r] * inv) + 128;
                rowp[col] = (unsigned char)q;
            }
        }
        if (c15 == 0) *(float*)(rowp + 100) = att[r] * mx * (1.0f / 127.0f);
        if (c15 < 6)  *(unsigned int*)(rowp + 104 + 4 * c15) = 0x80808080u;  // biased-zero pad
    }
}

__global__ __launch_bounds__(256) void k_gemm(const unsigned short* __restrict__ xbf,
                                              const unsigned short* __restrict__ wbf,
                                              const float* __restrict__ scores,
                                              const float* __restrict__ deg,
                                              unsigned char* __restrict__ m, int layer) {
    gemm_body(blockIdx.x, xbf, wbf, scores, deg, m, layer);
}

// ---------------- fused: CSR scatter (atomic-FREE, rowptr+pos) || gemm layer 0 --
//   [0, GNE_C)        : es[rowptr[row]+pos] = {col, raw val}
//   [GNE_C, +GGE_C)   : gemm layer 0
__global__ __launch_bounds__(256) void k_sg(const int* __restrict__ row, const int* __restrict__ col,
                                            const void* __restrict__ aval,
                                            const int* __restrict__ rowptr,
                                            const int* __restrict__ pos, int2* __restrict__ es,
                                            const unsigned short* __restrict__ xbf,
                                            const unsigned short* __restrict__ wbf,
                                            const float* __restrict__ scores,
                                            const float* __restrict__ deg,
                                            unsigned char* __restrict__ m) {
    int b = blockIdx.x;
    if (b < GNE_C) {
        int fav = probe_block(aval, 256);
        int e = b * 256 + threadIdx.x;
        if (e >= NE) return;
        int p = rowptr[row[e]] + pos[e];
        es[p] = make_int2(col[e], __float_as_int(ldf(aval, e, fav)));
    } else {
        gemm_body(b - GNE_C, xbf, wbf, scores, deg, m, 0);
    }
}

// ---------------- per-layer: SpMM gather, 1 row per VMEM instruction ------------
// Lane (slot=lane>>4, k=lane&15). Per 8-edge iter: 2 es dwordx2 + 2 dwordx2
// row gathers (16 lanes x 8 B = 128 B row, 2 lines). Lane k<=11 holds cols
// 8k..8k+7; lane 12: cols 96..99 + scale word (masked to biased-zero for
// dequant); lanes 13..15: 0x80 pad. Scale broadcast via __shfl from lane
// group+12. Biased dequant: acc = sum t*q, corrected by -128*sum(t) at the
// end. Dummy slots clamp to edge e-1 with weight 0. Fused: L2-normalize,
// fin RMW, next-layer exp(score), last-layer output.
// (R14 A/B: this 16-lane dwordx2 form beats 8-lane dwordx4 by 17us/dispatch --
//  the wide form saturates VALU at 77% on the wider unpack + 3-level reduce.)
__global__ __launch_bounds__(256) void k_spmm(const int* __restrict__ rowptr,
                                              const int2* __restrict__ es,
                                              const unsigned char* __restrict__ m,
                                              const float* __restrict__ wat,
                                              unsigned int* __restrict__ xbf,
                                              unsigned int* __restrict__ fin,
                                              float* __restrict__ scores,
                                              void* __restrict__ out, const int* flags,
                                              int last) {
    int lane = threadIdx.x & 63;
    int w = threadIdx.x >> 6;
    int r = blockIdx.x * 4 + w;               // grid exact: r < NN always
    int slot = lane >> 4, k = lane & 15;
    int s = rowptr[r], e = rowptr[r + 1];
    const char* mq = (const char*)m;
    int src12 = (lane & 48) + 12;             // scale-holder lane of this 16-group

    float acc[8] = {0.f, 0.f, 0.f, 0.f, 0.f, 0.f, 0.f, 0.f};
    float tsum = 0.f;
    for (int i = s; i < e; i += 8) {
        int i0 = i + slot, i1 = i + 4 + slot;
        int j0 = i0 < e - 1 ? i0 : e - 1;
        int j1 = i1 < e - 1 ? i1 : e - 1;
        int2 c0 = es[j0];
        int2 c1 = es[j1];
        float v0 = (i0 < e) ? __int_as_float(c0.y) : 0.f;
        float v1 = (i1 < e) ? __int_as_float(c1.y) : 0.f;
        uint2 u0 = *(const uint2*)(mq + (((size_t)c0.x) << 7) + (k << 3));
        uint2 u1 = *(const uint2*)(mq + (((size_t)c1.x) << 7) + (k << 3));
        float s0 = __uint_as_float(__shfl((int)u0.y, src12));
        float s1 = __uint_as_float(__shfl((int)u1.y, src12));
        float t0 = v0 * s0, t1 = v1 * s1;
        tsum += t0 + t1;
        unsigned int x0 = u0.x, y0 = (k == 12) ? 0x80808080u : u0.y;
        unsigned int x1 = u1.x, y1 = (k == 12) ? 0x80808080u : u1.y;
        acc[0] += t0 * ub0(x0); acc[1] += t0 * ub1(x0);
        acc[2] += t0 * ub2(x0); acc[3] += t0 * ub3(x0);
        acc[4] += t0 * ub0(y0); acc[5] += t0 * ub1(y0);
        acc[6] += t0 * ub2(y0); acc[7] += t0 * ub3(y0);
        acc[0] += t1 * ub0(x1); acc[1] += t1 * ub1(x1);
        acc[2] += t1 * ub2(x1); acc[3] += t1 * ub3(x1);
        acc[4] += t1 * ub0(y1); acc[5] += t1 * ub1(y1);
        acc[6] += t1 * ub2(y1); acc[7] += t1 * ub3(y1);
    }
    // reduce across the 4 edge slots; then remove the +128 bias
    #pragma unroll
    for (int t = 0; t < 8; t++) {
        acc[t] += __shfl_xor(acc[t], 16);
        acc[t] += __shfl_xor(acc[t], 32);
    }
    tsum += __shfl_xor(tsum, 16);
    tsum += __shfl_xor(tsum, 32);
    float corr = 128.0f * tsum;
    #pragma unroll
    for (int t = 0; t < 8; t++) acc[t] -= corr;

    // L2 norm over the row (pad positions are ~0; they feed zeroed W rows only)
    float sq = 0.f;
    #pragma unroll
    for (int t = 0; t < 8; t++) sq += acc[t] * acc[t];
    #pragma unroll
    for (int off = 8; off; off >>= 1) sq += __shfl_xor(sq, off);
    float rn = 1.f / fmaxf(sqrtf(sq), 1e-12f);
    float n[8];
    #pragma unroll
    for (int t = 0; t < 8; t++) n[t] = acc[t] * rn;

    float part = 0.f;
    if (slot == 0) {
        if (!last) {
            uint4 q;
            q.x = pack2bf(n[0], n[1]); q.y = pack2bf(n[2], n[3]);
            q.z = pack2bf(n[4], n[5]); q.w = pack2bf(n[6], n[7]);
            *(uint4*)(xbf + (size_t)r * 64 + k * 4) = q;   // 256 B row incl. ~zero pad
        }
        if (k <= 12) {
            // fin RMW: 50 uints/row, accessed as uint2 pairs (8 B aligned)
            unsigned int fu[4] = {0u, 0u, 0u, 0u};
            size_t fb = (size_t)r * 50 + k * 4;
            uint2 fa = *(const uint2*)(fin + fb);
            fu[0] = fa.x; fu[1] = fa.y;
            if (k < 12) {
                uint2 fbv = *(const uint2*)(fin + fb + 2);
                fu[2] = fbv.x; fu[3] = fbv.y;
            }
            float fn[8];
            #pragma unroll
            for (int t = 0; t < 4; t++) {
                fn[2 * t]     = bflo(fu[t]) + n[2 * t];
                fn[2 * t + 1] = bfhi(fu[t]) + n[2 * t + 1];
            }
            if (!last) {
                uint2 pa, pb;
                pa.x = pack2bf(fn[0], fn[1]); pa.y = pack2bf(fn[2], fn[3]);
                pb.x = pack2bf(fn[4], fn[5]); pb.y = pack2bf(fn[6], fn[7]);
                *(uint2*)(fin + fb) = pa;
                if (k < 12) *(uint2*)(fin + fb + 2) = pb;
                // next-layer attention score partial
                float4 w0 = *(const float4*)(wat + k * 8);
                float4 w1 = *(const float4*)(wat + k * 8 + 4);
                part = n[0] * w0.x + n[1] * w0.y + n[2] * w0.z + n[3] * w0.w
                     + n[4] * w1.x + n[5] * w1.y + n[6] * w1.z + n[7] * w1.w;
            } else {
                if (flags[0]) {
                    float4 A, B;
                    A.x = fn[0] * 0.25f; A.y = fn[1] * 0.25f; A.z = fn[2] * 0.25f; A.w = fn[3] * 0.25f;
                    B.x = fn[4] * 0.25f; B.y = fn[5] * 0.25f; B.z = fn[6] * 0.25f; B.w = fn[7] * 0.25f;
                    float* ob = (float*)out + (size_t)r * 100 + k * 8;
                    *(float4*)ob = A;
                    if (k < 12) *(float4*)(ob + 4) = B;
                } else {
                    uint2 pa, pb;
                    pa.x = pack2bf(fn[0] * 0.25f, fn[1] * 0.25f);
                    pa.y = pack2bf(fn[2] * 0.25f, fn[3] * 0.25f);
                    pb.x = pack2bf(fn[4] * 0.25f, fn[5] * 0.25f);
                    pb.y = pack2bf(fn[6] * 0.25f, fn[7] * 0.25f);
                    unsigned int* ob = (unsigned int*)out + (size_t)r * 50 + k * 4;
                    *(uint2*)ob = pa;
                    if (k < 12) *(uint2*)(ob + 2) = pb;
                }
            }
        }
    }
    if (!last) {
        #pragma unroll
        for (int off = 8; off; off >>= 1) part += __shfl_xor(part, off);
        if (lane == 0) scores[r] = expf(part);
    }
}

extern "C" void kernel_launch(void* const* d_in, const int* in_sizes, int n_in,
                              void* d_out, int out_size, void* d_ws, size_t ws_size,
                              hipStream_t stream) {
    const void* emb   = d_in[0];
    const void* aval  = d_in[1];
    const void* w_att = d_in[2];
    const void* w_itm = d_in[4];
    const int* arow = (const int*)d_in[5];
    const int* acol = (const int*)d_in[6];

    char* w = (char*)d_ws;
    unsigned int*   xbf    = (unsigned int*)(w + OFF_XB);
    unsigned char*  m      = (unsigned char*)(w + OFF_M);
    unsigned int*   fin    = (unsigned int*)(w + OFF_F);
    float*          deg    = (float*)(w + OFF_DEG);
    float*          scores = (float*)(w + OFF_SC);
    int2*           es     = (int2*) (w + OFF_ES);
    int*            pos    = (int*)  (w + OFF_POS);
    int*            counts = (int*)  (w + OFF_CNT);
    u64*            degfix = (u64*)  (w + OFF_DGF);
    int*            rowptr = (int*)  (w + OFF_RP);
    int*            bsum   = (int*)  (w + OFF_BS);
    int*            flags  = (int*)  (w + OFF_FLAG);
    float*          wat    = (float*)(w + OFF_WAT);
    unsigned short* wbf    = (unsigned short*)(w + OFF_WBF);

    const int GN   = (NN + 255) / 256;        // 391 (scanC)
    const int GSCN = (NN + 1023) / 1024;      // 98 scan blocks
    const int GINI = GW4_C + GCV_C;           // 25168 init blocks
    const int GSG  = GNE_C + GGE_C;           // 4688 scatter||gemm0 blocks

    // zero counts+degfix (contiguous) -- stream-ordered, graph-capturable
    hipMemsetAsync(w + OFF_CNT, 0, ZERO_BYTES, stream);

    k_init<<<GINI, 256, 0, stream>>>(emb, w_att, w_itm, xbf, fin, scores, flags,
                                     wat, wbf);
    k_deg<<<GNE_C, 256, 0, stream>>>(aval, arow, acol, degfix, counts, pos);
    k_scanA<<<GSCN, 256, 0, stream>>>(counts, rowptr, bsum, degfix, deg);
    k_scanC<<<GN, 256, 0, stream>>>(rowptr, bsum);
    k_sg<<<GSG, 256, 0, stream>>>(arow, acol, aval, rowptr, pos, es,
                                  (const unsigned short*)xbf, wbf, scores, deg, m);

    k_spmm<<<GW4_C, 256, 0, stream>>>(rowptr, es, m, wat, xbf, fin, scores,
                                      d_out, flags, 0);
    for (int l = 1; l < NL; l++) {
        k_gemm<<<GGE_C, 256, 0, stream>>>((const unsigned short*)xbf, wbf, scores, deg, m, l);
        k_spmm<<<GW4_C, 256, 0, stream>>>(rowptr, es, m, wat, xbf, fin, scores,
                                          d_out, flags, (l == NL - 1) ? 1 : 0);
    }
}